// Round 4
// baseline (287.436 us; speedup 1.0000x reference)
//
#include <hip/hip_runtime.h>

#define NB 4
#define NH 16
#define NSQ 1024
#define NSKV 1024
#define ND 64

typedef __attribute__((ext_vector_type(8))) short short8;
typedef __attribute__((ext_vector_type(4))) float f32x4;
typedef __attribute__((ext_vector_type(4))) int int4v;
typedef __attribute__((ext_vector_type(4))) unsigned int uint4v;
typedef __attribute__((ext_vector_type(2))) unsigned int uint2v;

__device__ __forceinline__ unsigned int cvt_pk(float lo, float hi) {
  unsigned int r;
  asm("v_cvt_pk_bf16_f32 %0, %1, %2" : "=v"(r) : "v"(lo), "v"(hi));
  return r;
}
__device__ __forceinline__ float bf2f(unsigned short h) {
  return __uint_as_float(((unsigned int)h) << 16);
}

// 128 threads = 2 independent waves, no __syncthreads. Wave owns 16 q-rows.
// SWAPPED QK^T: mfma(A=K, B=Q) so lane (lg,lm) holds P[q=lm][kv=sub*16+lg*4+j]
//  -> A/M loads are float4/int4 at exactly those positions, row-sum is
//     per-lane scalar, P writes to Ps are 2x ds_write_b64 per chunk.
// FIFO pipeline per 32-kv chunk n: [issue V(n)] [issue A/M/K(n+1)] [process(n)]
//  -> every wait is a counted vmcnt (prefetch stays in flight), never a drain.
// PV: pf = P[q=lm][kv0+lg*8..+7] from Ps (address-based transpose), B=V cols.
__global__ __launch_bounds__(128)
void attn_fused(const float* __restrict__ Q, const float* __restrict__ K,
                const float* __restrict__ V, const int* __restrict__ M,
                const float* __restrict__ A, float* __restrict__ Octx,
                float* __restrict__ Ow)
{
  __shared__ unsigned short Ps[32 * 1024];  // 64 KB, rows 2048B, byte-XOR (row&15)<<4
  __shared__ float RcpS[32];

  const int t  = threadIdx.x;
  const int w  = t >> 6;
  const int l  = t & 63;
  const int lg = l >> 4;       // 0..3
  const int lm = l & 15;

  const int bid = blockIdx.x;
  const int qt  = bid & 31;
  const int bh  = bid >> 5;
  const int b   = bh >> 4;
  const int q0  = qt * 32;
  const int qw  = q0 + w * 16;

  const float* Qp = Q + (size_t)bh * NSQ * ND;
  const float* Kp = K + (size_t)bh * NSKV * ND;
  const float* Vp = V + (size_t)bh * NSKV * ND;
  const float* Ap = A + (size_t)bh * NSQ * NSKV;
  const int*   Mp = M + (size_t)b  * NSQ * NSKV;

  const float C = 0.18033688011112042f;  // 0.125 * log2(e)

  // Q fragment (B operand of QK^T): lane holds Q[qw+lm][dc*32+lg*8+e]
  short8 qf[2];
  {
    const float* qr = Qp + (size_t)(qw + lm) * ND + lg * 8;
    #pragma unroll
    for (int dc = 0; dc < 2; ++dc) {
      f32x4 x = *(const f32x4*)(qr + dc * 32);
      f32x4 y = *(const f32x4*)(qr + dc * 32 + 4);
      uint4v u;
      u[0] = cvt_pk(x[0], x[1]); u[1] = cvt_pk(x[2], x[3]);
      u[2] = cvt_pk(y[0], y[1]); u[3] = cvt_pk(y[2], y[3]);
      qf[dc] = __builtin_bit_cast(short8, u);
    }
  }

  f32x4 ctx[4];
  #pragma unroll
  for (int i = 0; i < 4; ++i) ctx[i] = (f32x4){0.f, 0.f, 0.f, 0.f};
  float sum = 0.f;

  // prefetch buffers (A, M, K one chunk ahead; static double-buffer)
  f32x4 aA[2], aB[2];  int4v mA[2], mB[2];  f32x4 kA[8], kB[8];
  float vcur[32];      // V for the CURRENT chunk, issued before next prefetch

  auto loadAMK = [&](int kv0, f32x4* a, int4v* m, f32x4* k) {
    #pragma unroll
    for (int sub = 0; sub < 2; ++sub) {
      size_t off = (size_t)(qw + lm) * NSKV + (kv0 + sub * 16 + lg * 4);
      a[sub] = *(const f32x4*)(Ap + off);
      m[sub] = *(const int4v*)(Mp + off);
    }
    #pragma unroll
    for (int sub = 0; sub < 2; ++sub)
      #pragma unroll
      for (int dc = 0; dc < 2; ++dc) {
        const float* src = Kp + (size_t)(kv0 + sub * 16 + lm) * ND + dc * 32 + lg * 8;
        k[sub * 4 + dc * 2 + 0] = *(const f32x4*)src;
        k[sub * 4 + dc * 2 + 1] = *(const f32x4*)(src + 4);
      }
  };
  auto loadV = [&](int kv0, float* v) {
    #pragma unroll
    for (int ds = 0; ds < 4; ++ds)
      #pragma unroll
      for (int e = 0; e < 8; ++e)
        v[ds * 8 + e] = Vp[(size_t)(kv0 + lg * 8 + e) * ND + ds * 16 + lm];
  };

  auto process = [&](int kv0, const f32x4* a, const int4v* m, const f32x4* k,
                     const float* v) {
    // QK^T (A=K, B=Q): acc[j] = P-logit(q=lm, kv=kv0+sub*16+lg*4+j)
    #pragma unroll
    for (int sub = 0; sub < 2; ++sub) {
      f32x4 acc = (f32x4){0.f, 0.f, 0.f, 0.f};
      #pragma unroll
      for (int dc = 0; dc < 2; ++dc) {
        f32x4 x = k[sub * 4 + dc * 2 + 0], y = k[sub * 4 + dc * 2 + 1];
        uint4v u;
        u[0] = cvt_pk(x[0], x[1]); u[1] = cvt_pk(x[2], x[3]);
        u[2] = cvt_pk(y[0], y[1]); u[3] = cvt_pk(y[2], y[3]);
        acc = __builtin_amdgcn_mfma_f32_16x16x32_bf16(
            __builtin_bit_cast(short8, u), qf[dc], acc, 0, 0, 0);
      }
      float pe[4];
      #pragma unroll
      for (int j = 0; j < 4; ++j) {
        float amc = m[sub][j] ? a[sub][j] * C : -1.8e8f;
        pe[j] = exp2f(fmaf(acc[j], C, amc));  // masked -> exact 0
        sum += pe[j];
      }
      uint2v u2;
      u2[0] = cvt_pk(pe[0], pe[1]); u2[1] = cvt_pk(pe[2], pe[3]);
      int colb = (kv0 + sub * 16 + lg * 4) * 2;
      *(uint2v*)((char*)Ps + (w * 16 + lm) * 2048 + (colb ^ (lm << 4))) = u2;
    }
    // V fragments built BEFORE the LDS fence (overlaps the ds_writes)
    short8 vf[4];
    #pragma unroll
    for (int ds = 0; ds < 4; ++ds) {
      uint4v u;
      u[0] = cvt_pk(v[ds * 8 + 0], v[ds * 8 + 1]);
      u[1] = cvt_pk(v[ds * 8 + 2], v[ds * 8 + 3]);
      u[2] = cvt_pk(v[ds * 8 + 4], v[ds * 8 + 5]);
      u[3] = cvt_pk(v[ds * 8 + 6], v[ds * 8 + 7]);
      vf[ds] = __builtin_bit_cast(short8, u);
    }
    // own-wave Ps RAW fence (rule #18)
    asm volatile("s_waitcnt lgkmcnt(0)" ::: "memory");
    __builtin_amdgcn_sched_barrier(0);
    // PV: pf = P[q=lm][kv0+lg*8..+7] (address-based transpose via Ps)
    short8 pf = *(const short8*)((const char*)Ps + (w * 16 + lm) * 2048 +
                                 (((kv0 + lg * 8) * 2) ^ (lm << 4)));
    #pragma unroll
    for (int ds = 0; ds < 4; ++ds)
      ctx[ds] = __builtin_amdgcn_mfma_f32_16x16x32_bf16(pf, vf[ds], ctx[ds], 0, 0, 0);
  };

  // ---- FIFO-ordered pipeline ----
  loadAMK(0, aA, mA, kA);
  for (int kv0 = 0; kv0 < NSKV; kv0 += 64) {
    loadV(kv0, vcur);                      // V(n): oldest of this phase
    loadAMK(kv0 + 32, aB, mB, kB);         // prefetch n+1 (stays in flight)
    process(kv0, aA, mA, kA, vcur);
    loadV(kv0 + 32, vcur);
    if (kv0 + 64 < NSKV) loadAMK(kv0 + 64, aA, mA, kA);
    process(kv0 + 32, aB, mB, kB, vcur);
  }

  // ---- row sum: complete across the 4 lg-lanes sharing q=lm
  sum += __shfl_xor(sum, 16);
  sum += __shfl_xor(sum, 32);
  float rcp = 1.0f / sum;
  if (lg == 0) RcpS[w * 16 + lm] = rcp;
  asm volatile("s_waitcnt lgkmcnt(0)" ::: "memory");
  __builtin_amdgcn_sched_barrier(0);

  // ---- context out: need rcp for q=lg*4+j (via RcpS)
  float rcpj[4];
  #pragma unroll
  for (int j = 0; j < 4; ++j) rcpj[j] = RcpS[w * 16 + lg * 4 + j];
  #pragma unroll
  for (int ds = 0; ds < 4; ++ds)
    #pragma unroll
    for (int j = 0; j < 4; ++j)
      Octx[((size_t)bh * NSQ + qw + lg * 4 + j) * ND + ds * 16 + lm] =
          ctx[ds][j] * rcpj[j];

  // ---- weights out: wave writes its own 16 rows, b128 LDS reads, coalesced stores
  float* Owp = Ow + (size_t)bh * NSQ * NSKV + (size_t)qw * NSKV;
  for (int r = 0; r < 16; ++r) {
    float rr = RcpS[w * 16 + r];
    #pragma unroll
    for (int it = 0; it < 2; ++it) {
      int kv = it * 512 + l * 8;
      short8 p = *(const short8*)((const char*)Ps + (w * 16 + r) * 2048 +
                                  ((kv * 2) ^ (r << 4)));
      f32x4 o1, o2;
      o1[0] = bf2f((unsigned short)p[0]) * rr;
      o1[1] = bf2f((unsigned short)p[1]) * rr;
      o1[2] = bf2f((unsigned short)p[2]) * rr;
      o1[3] = bf2f((unsigned short)p[3]) * rr;
      o2[0] = bf2f((unsigned short)p[4]) * rr;
      o2[1] = bf2f((unsigned short)p[5]) * rr;
      o2[2] = bf2f((unsigned short)p[6]) * rr;
      o2[3] = bf2f((unsigned short)p[7]) * rr;
      *(f32x4*)&Owp[(size_t)r * NSKV + kv]     = o1;
      *(f32x4*)&Owp[(size_t)r * NSKV + kv + 4] = o2;
    }
  }
}

extern "C" void kernel_launch(void* const* d_in, const int* in_sizes, int n_in,
                              void* d_out, int out_size, void* d_ws, size_t ws_size,
                              hipStream_t stream) {
  const float* Q = (const float*)d_in[0];
  const float* K = (const float*)d_in[1];
  const float* V = (const float*)d_in[2];
  const int*   M = (const int*)d_in[3];
  const float* A = (const float*)d_in[4];
  float* ctx = (float*)d_out;
  float* wts = ctx + (size_t)NB * NH * NSQ * ND;  // outputs: (context, weights)
  dim3 grid(NB * NH * (NSQ / 32));
  attn_fused<<<grid, dim3(128), 0, stream>>>(Q, K, V, M, A, ctx, wts);
}

// Round 5
// 279.647 us; speedup vs baseline: 1.0279x; 1.0279x over previous
//
#include <hip/hip_runtime.h>

#define NB 4
#define NH 16
#define NSQ 1024
#define NSKV 1024
#define ND 64

typedef __attribute__((ext_vector_type(8))) short short8;
typedef __attribute__((ext_vector_type(4))) float f32x4;
typedef __attribute__((ext_vector_type(4))) int int4v;
typedef __attribute__((ext_vector_type(4))) unsigned int uint4v;
typedef __attribute__((ext_vector_type(2))) unsigned int uint2v;

__device__ __forceinline__ unsigned int cvt_pk(float lo, float hi) {
  unsigned int r;
  asm("v_cvt_pk_bf16_f32 %0, %1, %2" : "=v"(r) : "v"(lo), "v"(hi));
  return r;
}
__device__ __forceinline__ float bf2f(unsigned short h) {
  return __uint_as_float(((unsigned int)h) << 16);
}

// 512 threads = 8 waves. Wave w = (pair p=w&3, half h=w>>2): owns q-rows
// qw=q0+p*16 and kv half [h*512, h*512+512). 1 block/CU (145KB LDS) ->
// 8 waves/CU = 2/SIMD (2x R4's TLP). Sweep is barrier-free (disjoint Ps);
// one __syncthreads merges halves (sums + ctx partials) at the end.
// SWAPPED QK^T: mfma(A=K,B=Q) -> lane (lg,lm) holds P[q=lm][kv=s*16+lg*4+j].
// A/M (the HBM streams) prefetched a FULL chunk ahead (static double-buffer).
__global__ __launch_bounds__(512, 2)
void attn_fused(const float* __restrict__ Q, const float* __restrict__ K,
                const float* __restrict__ V, const int* __restrict__ M,
                const float* __restrict__ A, float* __restrict__ Octx,
                float* __restrict__ Ow)
{
  __shared__ unsigned short Ps[64 * 1024];  // 128 KB, rows 2048B, byte-XOR (row&15)<<4
  __shared__ float CtxS[4][16][64];         // 16 KB: h=1 ctx partials
  __shared__ float SumS[64][2];             // per-row partial sums by half

  const int t  = threadIdx.x;
  const int w  = t >> 6;
  const int l  = t & 63;
  const int lg = l >> 4;       // 0..3
  const int lm = l & 15;
  const int p  = w & 3;        // q-row pair id
  const int h  = w >> 2;       // kv half

  const int bid = blockIdx.x;
  const int qt  = bid & 15;    // SQ/64 tiles
  const int bh  = bid >> 4;    // 0..63
  const int b   = bh >> 4;
  const int q0  = qt * 64;
  const int qw  = q0 + p * 16;
  const int kvb = h * 512;

  const float* Qp = Q + (size_t)bh * NSQ * ND;
  const float* Kp = K + (size_t)bh * NSKV * ND;
  const float* Vp = V + (size_t)bh * NSKV * ND;
  const float* Ap = A + (size_t)bh * NSQ * NSKV;
  const int*   Mp = M + (size_t)b  * NSQ * NSKV;

  const float C = 0.18033688011112042f;  // 0.125 * log2(e)

  // Q fragment (B operand of QK^T): lane holds Q[qw+lm][dc*32+lg*8+e]
  short8 qf[2];
  {
    const float* qr = Qp + (size_t)(qw + lm) * ND + lg * 8;
    #pragma unroll
    for (int dc = 0; dc < 2; ++dc) {
      f32x4 x = *(const f32x4*)(qr + dc * 32);
      f32x4 y = *(const f32x4*)(qr + dc * 32 + 4);
      uint4v u;
      u[0] = cvt_pk(x[0], x[1]); u[1] = cvt_pk(x[2], x[3]);
      u[2] = cvt_pk(y[0], y[1]); u[3] = cvt_pk(y[2], y[3]);
      qf[dc] = __builtin_bit_cast(short8, u);
    }
  }

  f32x4 ctx[4];
  #pragma unroll
  for (int i = 0; i < 4; ++i) ctx[i] = (f32x4){0.f, 0.f, 0.f, 0.f};
  float sum = 0.f;

  f32x4 aA[2], aB[2];  int4v mA[2], mB[2];  // A/M double-buffer (static names)

  auto loadAM = [&](int kv0, f32x4* a, int4v* m) {
    #pragma unroll
    for (int sub = 0; sub < 2; ++sub) {
      size_t off = (size_t)(qw + lm) * NSKV + (kv0 + sub * 16 + lg * 4);
      a[sub] = *(const f32x4*)(Ap + off);
      m[sub] = *(const int4v*)(Mp + off);
    }
  };

  auto chunk = [&](int kv0, const f32x4* a, const int4v* m) {
    // K fragments (L2-hot): issued first, consumed after V-issue gap
    f32x4 k[8];
    #pragma unroll
    for (int sub = 0; sub < 2; ++sub)
      #pragma unroll
      for (int dc = 0; dc < 2; ++dc) {
        const float* src = Kp + (size_t)(kv0 + sub * 16 + lm) * ND + dc * 32 + lg * 8;
        k[sub * 4 + dc * 2 + 0] = *(const f32x4*)src;
        k[sub * 4 + dc * 2 + 1] = *(const f32x4*)(src + 4);
      }
    // V column fragments (L2-hot)
    float v[32];
    #pragma unroll
    for (int ds = 0; ds < 4; ++ds)
      #pragma unroll
      for (int e = 0; e < 8; ++e)
        v[ds * 8 + e] = Vp[(size_t)(kv0 + lg * 8 + e) * ND + ds * 16 + lm];

    // QK^T + exp -> Ps + per-lane partial sum
    #pragma unroll
    for (int sub = 0; sub < 2; ++sub) {
      f32x4 acc = (f32x4){0.f, 0.f, 0.f, 0.f};
      #pragma unroll
      for (int dc = 0; dc < 2; ++dc) {
        f32x4 x = k[sub * 4 + dc * 2 + 0], y = k[sub * 4 + dc * 2 + 1];
        uint4v u;
        u[0] = cvt_pk(x[0], x[1]); u[1] = cvt_pk(x[2], x[3]);
        u[2] = cvt_pk(y[0], y[1]); u[3] = cvt_pk(y[2], y[3]);
        acc = __builtin_amdgcn_mfma_f32_16x16x32_bf16(
            __builtin_bit_cast(short8, u), qf[dc], acc, 0, 0, 0);
      }
      float pe[4];
      #pragma unroll
      for (int j = 0; j < 4; ++j) {
        float amc = m[sub][j] ? a[sub][j] * C : -1.8e8f;
        pe[j] = exp2f(fmaf(acc[j], C, amc));  // masked -> exact 0
        sum += pe[j];
      }
      uint2v u2;
      u2[0] = cvt_pk(pe[0], pe[1]); u2[1] = cvt_pk(pe[2], pe[3]);
      int colb = (kv0 + sub * 16 + lg * 4) * 2;
      *(uint2v*)((char*)Ps + (p * 16 + lm) * 2048 + (colb ^ (lm << 4))) = u2;
    }
    // V fragments built before the LDS fence (overlaps the ds_writes)
    short8 vf[4];
    #pragma unroll
    for (int ds = 0; ds < 4; ++ds) {
      uint4v u;
      u[0] = cvt_pk(v[ds * 8 + 0], v[ds * 8 + 1]);
      u[1] = cvt_pk(v[ds * 8 + 2], v[ds * 8 + 3]);
      u[2] = cvt_pk(v[ds * 8 + 4], v[ds * 8 + 5]);
      u[3] = cvt_pk(v[ds * 8 + 6], v[ds * 8 + 7]);
      vf[ds] = __builtin_bit_cast(short8, u);
    }
    // own-wave Ps RAW fence (rule #18)
    asm volatile("s_waitcnt lgkmcnt(0)" ::: "memory");
    __builtin_amdgcn_sched_barrier(0);
    // PV: pf = P[q=lm][kv0+lg*8..+7] (address-based transpose via Ps)
    short8 pf = *(const short8*)((const char*)Ps + (p * 16 + lm) * 2048 +
                                 (((kv0 + lg * 8) * 2) ^ (lm << 4)));
    #pragma unroll
    for (int ds = 0; ds < 4; ++ds)
      ctx[ds] = __builtin_amdgcn_mfma_f32_16x16x32_bf16(pf, vf[ds], ctx[ds], 0, 0, 0);
  };

  // ---- sweep: 16 chunks of 32 kv, A/M prefetched a FULL chunk ahead ----
  loadAM(kvb, aA, mA);
  for (int c = 0; c < 16; c += 2) {
    loadAM(kvb + ((c + 1) & 15) * 32, aB, mB);   // in flight across chunk c
    chunk(kvb + c * 32, aA, mA);
    loadAM(kvb + ((c + 2) & 15) * 32, aA, mA);   // wraps harmlessly at end
    chunk(kvb + (c + 1) * 32, aB, mB);
  }

  // ---- merge halves ----
  sum += __shfl_xor(sum, 16);
  sum += __shfl_xor(sum, 32);
  if (lg == 0) SumS[p * 16 + lm][h] = sum;
  if (h == 1) {
    #pragma unroll
    for (int ds = 0; ds < 4; ++ds)
      #pragma unroll
      for (int j = 0; j < 4; ++j)
        CtxS[p][lg * 4 + j][ds * 16 + lm] = ctx[ds][j];
  }
  __syncthreads();

  if (h == 0) {
    float rcpj[4];
    #pragma unroll
    for (int j = 0; j < 4; ++j)
      rcpj[j] = 1.0f / (SumS[p * 16 + lg * 4 + j][0] + SumS[p * 16 + lg * 4 + j][1]);
    #pragma unroll
    for (int ds = 0; ds < 4; ++ds)
      #pragma unroll
      for (int j = 0; j < 4; ++j)
        Octx[((size_t)bh * NSQ + qw + lg * 4 + j) * ND + ds * 16 + lm] =
            (ctx[ds][j] + CtxS[p][lg * 4 + j][ds * 16 + lm]) * rcpj[j];
  }

  // ---- weights out: wave writes its own 16 rows x its 512-kv half ----
  float* Owp = Ow + (size_t)bh * NSQ * NSKV + (size_t)qw * NSKV;
  for (int r = 0; r < 16; ++r) {
    float rr = 1.0f / (SumS[p * 16 + r][0] + SumS[p * 16 + r][1]);
    int kv = kvb + l * 8;
    short8 pv = *(const short8*)((const char*)Ps + (p * 16 + r) * 2048 +
                                 ((kv * 2) ^ (r << 4)));
    f32x4 o1, o2;
    o1[0] = bf2f((unsigned short)pv[0]) * rr;
    o1[1] = bf2f((unsigned short)pv[1]) * rr;
    o1[2] = bf2f((unsigned short)pv[2]) * rr;
    o1[3] = bf2f((unsigned short)pv[3]) * rr;
    o2[0] = bf2f((unsigned short)pv[4]) * rr;
    o2[1] = bf2f((unsigned short)pv[5]) * rr;
    o2[2] = bf2f((unsigned short)pv[6]) * rr;
    o2[3] = bf2f((unsigned short)pv[7]) * rr;
    *(f32x4*)&Owp[(size_t)r * NSKV + kv]     = o1;
    *(f32x4*)&Owp[(size_t)r * NSKV + kv + 4] = o2;
  }
}

extern "C" void kernel_launch(void* const* d_in, const int* in_sizes, int n_in,
                              void* d_out, int out_size, void* d_ws, size_t ws_size,
                              hipStream_t stream) {
  const float* Q = (const float*)d_in[0];
  const float* K = (const float*)d_in[1];
  const float* V = (const float*)d_in[2];
  const int*   M = (const int*)d_in[3];
  const float* A = (const float*)d_in[4];
  float* ctx = (float*)d_out;
  float* wts = ctx + (size_t)NB * NH * NSQ * ND;  // outputs: (context, weights)
  dim3 grid(NB * NH * (NSQ / 64));
  attn_fused<<<grid, dim3(512), 0, stream>>>(Q, K, V, M, A, ctx, wts);
}

// Round 6
// 205.932 us; speedup vs baseline: 1.3958x; 1.3580x over previous
//
#include <hip/hip_runtime.h>

#define NB 4
#define NH 16
#define NSQ 1024
#define NSKV 1024
#define ND 64

typedef __attribute__((ext_vector_type(8))) short short8;
typedef __attribute__((ext_vector_type(4))) float f32x4;
typedef __attribute__((ext_vector_type(4))) int int4v;
typedef __attribute__((ext_vector_type(4))) unsigned int uint4v;
typedef __attribute__((ext_vector_type(2))) unsigned int uint2v;

__device__ __forceinline__ unsigned int cvt_pk(float lo, float hi) {
  unsigned int r;
  asm("v_cvt_pk_bf16_f32 %0, %1, %2" : "=v"(r) : "v"(lo), "v"(hi));
  return r;
}
__device__ __forceinline__ unsigned short f2bf(float f) {
  unsigned int u = __float_as_uint(f);
  u += 0x7FFFu + ((u >> 16) & 1u);
  return (unsigned short)(u >> 16);
}
__device__ __forceinline__ float bf2f(unsigned short h) {
  return __uint_as_float(((unsigned int)h) << 16);
}
__device__ __forceinline__ void bar() { __builtin_amdgcn_s_barrier(); }
__device__ __forceinline__ void lgkm0() {
  asm volatile("s_waitcnt lgkmcnt(0)" ::: "memory");
}

// 512 threads = 8 waves: (p = w&3) owns q-rows qw=q0+p*16; (h = w>>2) owns
// kv half. TRANSACTION-REDUCTION design: K/V chunks staged to LDS once per
// half with contiguous 16B/lane global loads (vs per-wave scattered fragment
// loads = ~5x fewer L1 transactions). Raw s_barrier + lgkmcnt-only drains so
// cross-chunk global prefetches (stage + A/M) stay in flight across barriers.
// SWAPPED QK^T: mfma(A=K,B=Q) -> lane (lg,lm) holds P[q=lm][kv=s*16+lg*4+j].
__global__ __launch_bounds__(512, 2)
void attn_fused(const float* __restrict__ Q, const float* __restrict__ K,
                const float* __restrict__ V, const int* __restrict__ M,
                const float* __restrict__ A, float* __restrict__ Octx,
                float* __restrict__ Ow)
{
  __shared__ unsigned short Ps[64 * 1024];       // 128 KB, rows 2048B, XOR (lm<<4)
  __shared__ __align__(16) unsigned char Stg[18432]; // staging; CtxS overlay post-sweep
  __shared__ float SumS[64][2];

  const int t  = threadIdx.x;
  const int w  = t >> 6;
  const int l  = t & 63;
  const int lg = l >> 4;       // 0..3
  const int lm = l & 15;
  const int p  = w & 3;        // q-row pair id
  const int h  = w >> 2;       // kv half
  const int g  = p * 64 + l;   // gang lane within half (0..255)

  const int bid = blockIdx.x;
  const int qt  = bid & 15;    // SQ/64 tiles
  const int bh  = bid >> 4;    // 0..63
  const int b   = bh >> 4;
  const int q0  = qt * 64;
  const int qw  = q0 + p * 16;
  const int kvb = h * 512;

  const float* Qp = Q + (size_t)bh * NSQ * ND;
  const float* Kp = K + (size_t)bh * NSKV * ND;
  const float* Vp = V + (size_t)bh * NSKV * ND;
  const float* Ap = A + (size_t)bh * NSQ * NSKV;
  const int*   Mp = M + (size_t)b  * NSQ * NSKV;

  unsigned char* KsB = Stg + h * 4096;           // [32 rows][128B], XOR (row&7)<<4
  unsigned char* VtB = Stg + 8192 + h * 5120;    // [64 d-rows][80B], XOR ((d>>2)&3)<<4

  const float C = 0.18033688011112042f;  // 0.125 * log2(e)

  // Q fragment (B operand of QK^T): lane holds Q[qw+lm][dc*32+lg*8+e]
  short8 qf[2];
  {
    const float* qr = Qp + (size_t)(qw + lm) * ND + lg * 8;
    #pragma unroll
    for (int dc = 0; dc < 2; ++dc) {
      f32x4 x = *(const f32x4*)(qr + dc * 32);
      f32x4 y = *(const f32x4*)(qr + dc * 32 + 4);
      uint4v u;
      u[0] = cvt_pk(x[0], x[1]); u[1] = cvt_pk(x[2], x[3]);
      u[2] = cvt_pk(y[0], y[1]); u[3] = cvt_pk(y[2], y[3]);
      qf[dc] = __builtin_bit_cast(short8, u);
    }
  }

  f32x4 ctx[4];
  #pragma unroll
  for (int i = 0; i < 4; ++i) ctx[i] = (f32x4){0.f, 0.f, 0.f, 0.f};
  float sum = 0.f;

  f32x4 aA[2], aB[2];  int4v mA[2], mB[2];       // A/M chunk-ahead double-buffer
  f32x4 skA[2], svA[2], skB[2], svB[2];          // staging chunk-ahead prefetch

  auto loadAM = [&](int kv0, f32x4* a, int4v* m) {
    #pragma unroll
    for (int sub = 0; sub < 2; ++sub) {
      size_t off = (size_t)(qw + lm) * NSKV + (kv0 + sub * 16 + lg * 4);
      a[sub] = *(const f32x4*)(Ap + off);
      m[sub] = *(const int4v*)(Mp + off);
    }
  };
  // chunk is 32 rows x 64 f32 = 2048 f32 CONTIGUOUS; gang lane takes items g, g+256
  auto issueStage = [&](int kv0, f32x4* sk, f32x4* sv) {
    const float* kb = Kp + (size_t)kv0 * ND;
    const float* vb = Vp + (size_t)kv0 * ND;
    sk[0] = *(const f32x4*)(kb + g * 4);
    sk[1] = *(const f32x4*)(kb + 1024 + g * 4);
    sv[0] = *(const f32x4*)(vb + g * 4);
    sv[1] = *(const f32x4*)(vb + 1024 + g * 4);
  };
  auto writeStage = [&](const f32x4* sk, const f32x4* sv) {
    #pragma unroll
    for (int i = 0; i < 2; ++i) {
      int f = g * 4 + i * 1024;
      int row = f >> 6;                 // kv-local
      int cb  = (f & 63) * 2;           // byte col in 128B row (8B-aligned)
      uint2v u;
      u[0] = cvt_pk(sk[i][0], sk[i][1]);
      u[1] = cvt_pk(sk[i][2], sk[i][3]);
      *(uint2v*)(KsB + row * 128 + (cb ^ ((row & 7) << 4))) = u;
      int kv = row, d0 = f & 63;
      #pragma unroll
      for (int j = 0; j < 4; ++j) {
        int d = d0 + j;
        *(unsigned short*)(VtB + d * 80 + ((kv * 2) ^ (((d >> 2) & 3) << 4))) =
            f2bf(sv[i][j]);
      }
    }
  };

  auto chunk = [&](int kv0, const f32x4* a, const int4v* m) {
    const int ksw = (lm & 7) << 4;
    const int vsw = ((lm >> 2) & 3) << 4;
    // fragments from LDS (bf16 already): 4+4 ds_read_b128, ~2-way max
    short8 kf[4];
    #pragma unroll
    for (int sub = 0; sub < 2; ++sub)
      #pragma unroll
      for (int dc = 0; dc < 2; ++dc)
        kf[sub * 2 + dc] = *(const short8*)(
            KsB + (sub * 16 + lm) * 128 + ((dc * 64 + lg * 16) ^ ksw));
    short8 vf[4];
    #pragma unroll
    for (int ds = 0; ds < 4; ++ds)
      vf[ds] = *(const short8*)(VtB + (ds * 16 + lm) * 80 + ((lg * 16) ^ vsw));

    // QK^T (A=K,B=Q): acc[j] = logit(q=lm, kv=kv0+sub*16+lg*4+j)
    #pragma unroll
    for (int sub = 0; sub < 2; ++sub) {
      f32x4 acc = (f32x4){0.f, 0.f, 0.f, 0.f};
      #pragma unroll
      for (int dc = 0; dc < 2; ++dc)
        acc = __builtin_amdgcn_mfma_f32_16x16x32_bf16(kf[sub * 2 + dc], qf[dc],
                                                      acc, 0, 0, 0);
      float pe[4];
      #pragma unroll
      for (int j = 0; j < 4; ++j) {
        float amc = m[sub][j] ? a[sub][j] * C : -1.8e8f;
        pe[j] = exp2f(fmaf(acc[j], C, amc));  // masked -> exact 0
        sum += pe[j];
      }
      uint2v u2;
      u2[0] = cvt_pk(pe[0], pe[1]); u2[1] = cvt_pk(pe[2], pe[3]);
      int colb = (kv0 + sub * 16 + lg * 4) * 2;
      *(uint2v*)((char*)Ps + (p * 16 + lm) * 2048 + (colb ^ (lm << 4))) = u2;
    }
    // own-wave Ps RAW fence (rule #18)
    lgkm0();
    __builtin_amdgcn_sched_barrier(0);
    // PV: pf = P[q=lm][kv0+lg*8..+7]
    short8 pf = *(const short8*)((const char*)Ps + (p * 16 + lm) * 2048 +
                                 (((kv0 + lg * 8) * 2) ^ (lm << 4)));
    #pragma unroll
    for (int ds = 0; ds < 4; ++ds)
      ctx[ds] = __builtin_amdgcn_mfma_f32_16x16x32_bf16(pf, vf[ds], ctx[ds], 0, 0, 0);
  };

  // ---- sweep: 16 chunks of 32 kv; staging + A/M prefetched a chunk ahead ----
  issueStage(kvb, skA, svA);
  loadAM(kvb, aA, mA);
  for (int c = 0; c < 16; c += 2) {
    int kv0 = kvb + c * 32;
    bar();                               // staging buffer free
    writeStage(skA, svA);                // vmcnt wait on skA (issued a chunk ago)
    issueStage(kv0 + 32, skB, svB);      // in flight across chunk c
    loadAM(kv0 + 32, aB, mB);
    lgkm0(); bar();                      // staging visible (vm prefetches stay live)
    chunk(kv0, aA, mA);
    bar();
    writeStage(skB, svB);
    if (c < 14) { issueStage(kv0 + 64, skA, svA); loadAM(kv0 + 64, aA, mA); }
    lgkm0(); bar();
    chunk(kv0 + 32, aB, mB);
  }

  // ---- merge halves ----
  sum += __shfl_xor(sum, 16);
  sum += __shfl_xor(sum, 32);
  if (lg == 0) SumS[p * 16 + lm][h] = sum;
  lgkm0(); bar();                        // SumS visible; staging readers all done

  float (*CtxS)[16][64] = (float(*)[16][64])Stg;   // overlay staging area
  if (h == 1) {
    #pragma unroll
    for (int ds = 0; ds < 4; ++ds)
      #pragma unroll
      for (int j = 0; j < 4; ++j)
        CtxS[p][lg * 4 + j][ds * 16 + lm] = ctx[ds][j];
  }
  lgkm0(); bar();

  if (h == 0) {
    float rcpj[4];
    #pragma unroll
    for (int j = 0; j < 4; ++j) {
      int r = p * 16 + lg * 4 + j;
      rcpj[j] = 1.0f / (SumS[r][0] + SumS[r][1]);
    }
    #pragma unroll
    for (int ds = 0; ds < 4; ++ds)
      #pragma unroll
      for (int j = 0; j < 4; ++j)
        Octx[((size_t)bh * NSQ + qw + lg * 4 + j) * ND + ds * 16 + lm] =
            (ctx[ds][j] + CtxS[p][lg * 4 + j][ds * 16 + lm]) * rcpj[j];
  }

  // ---- weights out: wave writes its own 16 rows x its 512-kv half ----
  float* Owp = Ow + (size_t)bh * NSQ * NSKV + (size_t)qw * NSKV;
  for (int r = 0; r < 16; ++r) {
    float rr = 1.0f / (SumS[p * 16 + r][0] + SumS[p * 16 + r][1]);
    int kv = kvb + l * 8;
    short8 pv = *(const short8*)((const char*)Ps + (p * 16 + r) * 2048 +
                                 ((kv * 2) ^ (r << 4)));
    f32x4 o1, o2;
    o1[0] = bf2f((unsigned short)pv[0]) * rr;
    o1[1] = bf2f((unsigned short)pv[1]) * rr;
    o1[2] = bf2f((unsigned short)pv[2]) * rr;
    o1[3] = bf2f((unsigned short)pv[3]) * rr;
    o2[0] = bf2f((unsigned short)pv[4]) * rr;
    o2[1] = bf2f((unsigned short)pv[5]) * rr;
    o2[2] = bf2f((unsigned short)pv[6]) * rr;
    o2[3] = bf2f((unsigned short)pv[7]) * rr;
    *(f32x4*)&Owp[(size_t)r * NSKV + kv]     = o1;
    *(f32x4*)&Owp[(size_t)r * NSKV + kv + 4] = o2;
  }
}

extern "C" void kernel_launch(void* const* d_in, const int* in_sizes, int n_in,
                              void* d_out, int out_size, void* d_ws, size_t ws_size,
                              hipStream_t stream) {
  const float* Q = (const float*)d_in[0];
  const float* K = (const float*)d_in[1];
  const float* V = (const float*)d_in[2];
  const int*   M = (const int*)d_in[3];
  const float* A = (const float*)d_in[4];
  float* ctx = (float*)d_out;
  float* wts = ctx + (size_t)NB * NH * NSQ * ND;  // outputs: (context, weights)
  dim3 grid(NB * NH * (NSQ / 64));
  attn_fused<<<grid, dim3(512), 0, stream>>>(Q, K, V, M, A, ctx, wts);
}